// Round 7
// baseline (82.516 us; speedup 1.0000x reference)
//
#include <hip/hip_runtime.h>
#include <math.h>

#define NCLS 81
#define A_ANCH 8732
#define B_BATCH 64
#define NANCH (B_BATCH * A_ANCH)   // 558,848 anchors
#define EPSF 1e-7f

#define ROWS_PT 4                  // anchors per thread: 4*81 floats = 81 aligned float4
#define NTH (NANCH / ROWS_PT)      // 139,712 threads (exact)
#define L1_BLK 64
#define L1_GRID (NTH / L1_BLK)     // 2,183 blocks (exact)

// ---------------- workspace layout ----------------
// [0]      sout : NANCH floats (-logp0 per anchor)
// [SBYTES] accum: 2 doubles (conf_sum, loc_sum)
// [+16]    hits : 1 ull
static const size_t SBYTES = (size_t)NANCH * sizeof(float);

// ---------------- K1: streaming -logp0 per anchor, registers only ----------------
// No LDS, no manual pipelining: pure float4 register loads + 16 waves/CU TLP,
// the same regime as the 6.3 TB/s copy microbenchmark. Alignment guaranteed by
// processing 4 rows/thread (1296 B % 16 == 0).
__global__ __launch_bounds__(L1_BLK, 4) void lse4_kernel(
    const float* __restrict__ conf, float* __restrict__ sout,
    double* __restrict__ accum, unsigned long long* __restrict__ hits)
{
    if (blockIdx.x == 0 && threadIdx.x == 0) {   // consumers run in later kernels
        accum[0] = 0.0; accum[1] = 0.0; *hits = 0ull;
    }
    int t = blockIdx.x * L1_BLK + threadIdx.x;   // < NTH by construction
    const float4* p = (const float4*)conf + (size_t)t * 81;

    float s0 = 0.f, s1 = 0.f, s2 = 0.f, s3 = 0.f;
    float x00 = 0.f, x01 = 0.f, x02 = 0.f, x03 = 0.f;

    #pragma unroll
    for (int k = 0; k < 81; ++k) {
        float4 q = p[k];
        // element e = 4k+i; row = e/81, cls = e%81 — all compile-time constants
        {   const int e = 4 * k + 0, r = e / NCLS, c = e % NCLS;
            float ev = __expf(q.x);
            if (r == 0) { s0 += ev; if (c == 0) x00 = q.x; }
            else if (r == 1) { s1 += ev; if (c == 0) x01 = q.x; }
            else if (r == 2) { s2 += ev; if (c == 0) x02 = q.x; }
            else             { s3 += ev; if (c == 0) x03 = q.x; } }
        {   const int e = 4 * k + 1, r = e / NCLS, c = e % NCLS;
            float ev = __expf(q.y);
            if (r == 0) { s0 += ev; if (c == 0) x00 = q.y; }
            else if (r == 1) { s1 += ev; if (c == 0) x01 = q.y; }
            else if (r == 2) { s2 += ev; if (c == 0) x02 = q.y; }
            else             { s3 += ev; if (c == 0) x03 = q.y; } }
        {   const int e = 4 * k + 2, r = e / NCLS, c = e % NCLS;
            float ev = __expf(q.z);
            if (r == 0) { s0 += ev; if (c == 0) x02 = x02; }
            else if (r == 1) { s1 += ev; }
            else if (r == 2) { s2 += ev; if (c == 0) x02 = q.z; }
            else             { s3 += ev; } }
        {   const int e = 4 * k + 3, r = e / NCLS, c = e % NCLS;
            float ev = __expf(q.w);
            if (r == 0) { s0 += ev; }
            else if (r == 1) { s1 += ev; }
            else if (r == 2) { s2 += ev; }
            else             { s3 += ev; if (c == 0) x03 = q.w; } }
    }
    // x00: e=0 (k=0,x); x01: e=81 (k=20,y); x02: e=162 (k=40,z); x03: e=243 (k=60,w)

    float4 o;
    o.x = __logf(s0) - x00;
    o.y = __logf(s1) - x01;
    o.z = __logf(s2) - x02;
    o.w = __logf(s3) - x03;
    ((float4*)sout)[t] = o;
}

// ---------------- K2: per-batch positives + hard-negative mining ----------------
#define K2_T 512
#define VPT 18   // 512*18 = 9216 >= 8732

__global__ __launch_bounds__(K2_T) void mine_kernel(
    const float* __restrict__ conf, const float* __restrict__ loc,
    const float* __restrict__ tgt, const float* __restrict__ sout,
    double* __restrict__ accum, unsigned long long* __restrict__ hits)
{
    __shared__ int   cnt[34];   // slots 0..30: bisect iters, 32: c0, 33: cg
    __shared__ float fs[4];     // 0: sall, 1: sg, 2: pos_ce, 3: pos_loc
    __shared__ int   nm_s;
    int b = blockIdx.x, tid = threadIdx.x, lane = tid & 63;
    if (tid < 34) cnt[tid] = 0;
    if (tid < 4)  fs[tid] = 0.f;
    if (tid == 0) nm_s = 0;
    __syncthreads();

    float v[VPT]; int lab[VPT];
    size_t base = (size_t)b * A_ANCH;
    #pragma unroll
    for (int i = 0; i < VPT; ++i) {
        int idx = tid + i * K2_T;
        bool in = idx < A_ANCH;
        v[i]   = in ? sout[base + idx] : -1.f;
        lab[i] = in ? (int)tgt[(base + idx) * 5 + 4] : 0;
    }

    // ---- positives: CE correction + GIoU; mask out of mining ----
    float pce = 0.f, ploc = 0.f; int pc = 0;
    #pragma unroll
    for (int i = 0; i < VPT; ++i) {
        if (lab[i] > 0) {
            size_t gi = base + (size_t)(tid + i * K2_T);
            float r0 = conf[gi * NCLS];
            float rl = conf[gi * NCLS + lab[i]];
            pce += v[i] + r0 - rl;       // ce = (lse - r0) + r0 - rl
            float4 p = *(const float4*)(loc + gi * 4);
            const float* tg = tgt + gi * 5;
            float tx1 = tg[0], ty1 = tg[1], tx2 = tg[2], ty2 = tg[3];
            float area_p = (p.z - p.x) * (p.w - p.y);
            float area_t = (tx2 - tx1) * (ty2 - ty1);
            float iw = fmaxf(fminf(p.z, tx2) - fmaxf(p.x, tx1), 0.f);
            float ih = fmaxf(fminf(p.w, ty2) - fmaxf(p.y, ty1), 0.f);
            float inter = iw * ih;
            float uni   = area_p + area_t - inter;
            float iou   = inter / (uni + EPSF);
            float cw = fmaxf(p.z, tx2) - fminf(p.x, tx1);
            float ch = fmaxf(p.w, ty2) - fminf(p.y, ty1);
            float area_c = cw * ch;
            ploc += 1.f - (iou - (area_c - uni) / (area_c + EPSF));
            pc++;
            v[i] = -1.f;                 // exclude from mining
        }
    }
    for (int off = 32; off; off >>= 1) {
        pc   += __shfl_xor(pc, off);
        pce  += __shfl_xor(pce, off);
        ploc += __shfl_xor(ploc, off);
    }
    if (lane == 0) {
        if (pc) atomicAdd(&nm_s, pc);
        atomicAdd(&fs[2], pce);
        atomicAdd(&fs[3], ploc);
    }

    // ---- count & sum of all mining candidates (v >= 0) ----
    int c = 0; float sa = 0.f;
    #pragma unroll
    for (int i = 0; i < VPT; ++i) { if (v[i] >= 0.f) { c++; sa += v[i]; } }
    for (int off = 32; off; off >>= 1) { c += __shfl_xor(c, off); sa += __shfl_xor(sa, off); }
    if (lane == 0) { atomicAdd(&cnt[32], c); atomicAdd(&fs[0], sa); }
    __syncthreads();

    int k = 3 * nm_s;
    int c0 = cnt[32]; float sall = fs[0];
    float negl = 0.f;
    if (k >= c0) {
        negl = sall;
    } else if (k > 0) {
        // bisect IEEE bits for the k-th largest candidate (values > 0)
        unsigned lo = 0u, hi = 0x7F800000u;
        int it = 0;
        while (hi - lo > 1u) {           // 31 uniform iterations
            unsigned mid = lo + (hi - lo) / 2u;
            float thr = __uint_as_float(mid);
            int cc = 0;
            #pragma unroll
            for (int i = 0; i < VPT; ++i) cc += (v[i] >= thr) ? 1 : 0;
            for (int off = 32; off; off >>= 1) cc += __shfl_xor(cc, off);
            if (lane == 0) atomicAdd(&cnt[it], cc);
            __syncthreads();
            if (cnt[it] >= k) lo = mid; else hi = mid;
            ++it;
        }
        float tth = __uint_as_float(lo); // exact k-th largest value
        int cg = 0; float sg = 0.f;
        #pragma unroll
        for (int i = 0; i < VPT; ++i) { if (v[i] > tth) { cg++; sg += v[i]; } }
        for (int off = 32; off; off >>= 1) { cg += __shfl_xor(cg, off); sg += __shfl_xor(sg, off); }
        if (lane == 0) { atomicAdd(&cnt[33], cg); atomicAdd(&fs[1], sg); }
        __syncthreads();
        negl = fs[1] + (float)(k - cnt[33]) * tth;   // ties contribute value tth
    }

    if (tid == 0) {
        atomicAdd(&accum[0], (double)(fs[2] + negl));
        atomicAdd(&accum[1], (double)fs[3]);
        atomicAdd(hits, (unsigned long long)nm_s);
    }
}

// ---------------- K3: finalize ----------------
__global__ void finalize_kernel(const double* __restrict__ accum,
                                const unsigned long long* __restrict__ hits,
                                float* __restrict__ out) {
    if (threadIdx.x == 0 && blockIdx.x == 0) {
        double conf_s = accum[0], loc_s = accum[1];
        unsigned long long h = *hits;
        double denom = (double)(h > 0 ? h : 1ull);
        if (h > 0) {
            out[0] = (float)((conf_s + loc_s) / denom);
            out[1] = (float)(conf_s / denom);
            out[2] = (float)(loc_s / denom);
        } else {
            out[0] = 0.f; out[1] = 0.f; out[2] = 0.f;
        }
    }
}

extern "C" void kernel_launch(void* const* d_in, const int* in_sizes, int n_in,
                              void* d_out, int out_size, void* d_ws, size_t ws_size,
                              hipStream_t stream) {
    const float* conf = (const float*)d_in[0];
    const float* loc  = (const float*)d_in[1];
    const float* tgt  = (const float*)d_in[2];
    float* out = (float*)d_out;

    char* ws = (char*)d_ws;
    float* sout = (float*)ws;
    double* accum = (double*)(ws + SBYTES);
    unsigned long long* hits = (unsigned long long*)(ws + SBYTES + 16);

    lse4_kernel<<<dim3(L1_GRID), dim3(L1_BLK), 0, stream>>>(conf, sout, accum, hits);
    mine_kernel<<<dim3(B_BATCH), dim3(K2_T), 0, stream>>>(
        conf, loc, tgt, sout, accum, hits);
    finalize_kernel<<<1, 64, 0, stream>>>(accum, hits, out);
}

// Round 8
// 61.633 us; speedup vs baseline: 1.3388x; 1.3388x over previous
//
#include <hip/hip_runtime.h>
#include <math.h>

#define NCLS 81
#define A_ANCH 8732
#define B_BATCH 64
#define NANCH (B_BATCH * A_ANCH)   // 558,848 anchors
#define EPSF 1e-7f

// ---- K1 tiling: 32 anchors/tile, register-staged, double-buffered LDS ----
#define TILE 32
#define TDW  (TILE * NCLS)      // 2592 dwords = 10368 B, 16B-aligned per tile
#define BUFDW 2624              // 10*256 + 64 (tail chunk region)
#define NT (NANCH / TILE)       // 17,464 tiles (exact)
#define GRID1 1792              // 7 blocks/CU * 256 CU (2x2624x4 = 21KB LDS/block)

// ---------------- workspace layout ----------------
// [0]      sout : NANCH floats (-logp0 per anchor)
// [SBYTES] accum: 2 doubles (conf_sum, loc_sum)
// [+16]    hits : 1 ull
static const size_t SBYTES = (size_t)NANCH * sizeof(float);

// ---------------- K1: streaming -logp0 (lse - x0) per anchor ----------------
// Register path (NOT global_load_lds): 10x lane-contiguous global_load_dwordx4
// (1 KB/instr, the 6.3 TB/s copy regime) + guarded 32-dword tail -> named VGPRs
// -> ds_write_b128 into the other LDS buffer. Loads for tile t+1 are issued
// BEFORE the compute on tile t; the compiler's auto s_waitcnt vmcnt(0) before
// the ds_write is the pipeline wait, covered by ~500 cyc of compute + 7-wave TLP.
__global__ __launch_bounds__(64) void lse_kernel(
    const float* __restrict__ conf, float* __restrict__ sout,
    double* __restrict__ accum, unsigned long long* __restrict__ hits)
{
    __shared__ float sb[2][BUFDW];   // 20,992 B -> 7 blocks/CU

    int tid = threadIdx.x;
    if (blockIdx.x == 0 && tid == 0) {   // consumers run in later kernels
        accum[0] = 0.0; accum[1] = 0.0; *hits = 0ull;
    }

    int a = tid & 31, h = tid >> 5;  // 2 lanes/anchor: h=0 -> cls 0..39, h=1 -> 40..80
    int t = blockIdx.x;

    float4 q0, q1, q2, q3, q4, q5, q6, q7, q8, q9;
    float qt = 0.f;

    // prologue: load tile t -> regs -> LDS[0]
    {
        const float4* p = (const float4*)conf + (size_t)t * (TDW / 4);
        q0 = p[0 * 64 + tid]; q1 = p[1 * 64 + tid]; q2 = p[2 * 64 + tid];
        q3 = p[3 * 64 + tid]; q4 = p[4 * 64 + tid]; q5 = p[5 * 64 + tid];
        q6 = p[6 * 64 + tid]; q7 = p[7 * 64 + tid]; q8 = p[8 * 64 + tid];
        q9 = p[9 * 64 + tid];
        if (tid < 32) qt = conf[(size_t)t * TDW + 2560 + tid];
        float4* lp = (float4*)&sb[0][0];
        lp[0 * 64 + tid] = q0; lp[1 * 64 + tid] = q1; lp[2 * 64 + tid] = q2;
        lp[3 * 64 + tid] = q3; lp[4 * 64 + tid] = q4; lp[5 * 64 + tid] = q5;
        lp[6 * 64 + tid] = q6; lp[7 * 64 + tid] = q7; lp[8 * 64 + tid] = q8;
        lp[9 * 64 + tid] = q9;
        if (tid < 32) sb[0][2560 + tid] = qt;
    }
    int par = 0;

    #pragma clang loop unroll(disable)
    while (true) {
        int tn = t + GRID1;
        bool more = (tn < NT);
        if (more) {   // issue next tile's loads; they fly during the compute below
            const float4* p = (const float4*)conf + (size_t)tn * (TDW / 4);
            q0 = p[0 * 64 + tid]; q1 = p[1 * 64 + tid]; q2 = p[2 * 64 + tid];
            q3 = p[3 * 64 + tid]; q4 = p[4 * 64 + tid]; q5 = p[5 * 64 + tid];
            q6 = p[6 * 64 + tid]; q7 = p[7 * 64 + tid]; q8 = p[8 * 64 + tid];
            q9 = p[9 * 64 + tid];
            if (tid < 32) qt = conf[(size_t)tn * TDW + 2560 + tid];
        }

        // ---- compute tile t from sb[par] ----
        const float* r = &sb[par][a * 81 + h * 40];   // stride-81: 2-way alias = free
        float x0 = r[0];                 // h=0 lane: class 0
        float s0 = 0.f, s1 = 0.f, s2 = 0.f, s3 = 0.f;
        #pragma unroll
        for (int j = 0; j < 40; j += 4) {
            s0 += __expf(r[j]);
            s1 += __expf(r[j + 1]);
            s2 += __expf(r[j + 2]);
            s3 += __expf(r[j + 3]);
        }
        float s = (s0 + s1) + (s2 + s3) + (float)h * __expf(r[40]);  // h=1 adds cls 80
        s += __shfl_xor(s, 32);          // combine the two half-rows
        float res = __logf(s) - x0;      // valid on h==0 lanes

        if (!more) {
            if (h == 0) sout[(size_t)t * TILE + a] = res;
            break;
        }

        // ds_write of next tile: compiler emits s_waitcnt vmcnt(0) right here,
        // waiting only on the 11 loads above (prev iter's store is long retired).
        {
            float4* lp = (float4*)&sb[par ^ 1][0];
            lp[0 * 64 + tid] = q0; lp[1 * 64 + tid] = q1; lp[2 * 64 + tid] = q2;
            lp[3 * 64 + tid] = q3; lp[4 * 64 + tid] = q4; lp[5 * 64 + tid] = q5;
            lp[6 * 64 + tid] = q6; lp[7 * 64 + tid] = q7; lp[8 * 64 + tid] = q8;
            lp[9 * 64 + tid] = q9;
            if (tid < 32) sb[par ^ 1][2560 + tid] = qt;
        }
        if (h == 0) sout[(size_t)t * TILE + a] = res;   // after ds_write: ack overlaps next iter

        t = tn; par ^= 1;
    }
}

// ---------------- K2: per-batch positives + hard-negative mining ----------------
#define K2_T 1024
#define VPT 9   // ceil(8732/1024)

__global__ __launch_bounds__(K2_T) void mine_kernel(
    const float* __restrict__ conf, const float* __restrict__ loc,
    const float* __restrict__ tgt, const float* __restrict__ sout,
    double* __restrict__ accum, unsigned long long* __restrict__ hits)
{
    __shared__ int   cnt[34];   // slots 0..30: bisect iters, 32: c0, 33: cg
    __shared__ float fs[4];     // 0: sall, 1: sg, 2: pos_ce, 3: pos_loc
    __shared__ int   nm_s;
    int b = blockIdx.x, tid = threadIdx.x, lane = tid & 63;
    if (tid < 34) cnt[tid] = 0;
    if (tid < 4)  fs[tid] = 0.f;
    if (tid == 0) nm_s = 0;
    __syncthreads();

    float v[VPT]; int lab[VPT];
    size_t base = (size_t)b * A_ANCH;
    #pragma unroll
    for (int i = 0; i < VPT; ++i) {
        int idx = tid + i * K2_T;
        bool in = idx < A_ANCH;
        v[i]   = in ? sout[base + idx] : -1.f;
        lab[i] = in ? (int)tgt[(base + idx) * 5 + 4] : 0;
    }

    // ---- positives: CE correction + GIoU; mask out of mining ----
    float pce = 0.f, ploc = 0.f; int pc = 0;
    #pragma unroll
    for (int i = 0; i < VPT; ++i) {
        if (lab[i] > 0) {
            size_t gi = base + (size_t)(tid + i * K2_T);
            float r0 = conf[gi * NCLS];
            float rl = conf[gi * NCLS + lab[i]];
            pce += v[i] + r0 - rl;       // ce = (lse - r0) + r0 - rl
            float4 p = *(const float4*)(loc + gi * 4);
            const float* tg = tgt + gi * 5;
            float tx1 = tg[0], ty1 = tg[1], tx2 = tg[2], ty2 = tg[3];
            float area_p = (p.z - p.x) * (p.w - p.y);
            float area_t = (tx2 - tx1) * (ty2 - ty1);
            float iw = fmaxf(fminf(p.z, tx2) - fmaxf(p.x, tx1), 0.f);
            float ih = fmaxf(fminf(p.w, ty2) - fmaxf(p.y, ty1), 0.f);
            float inter = iw * ih;
            float uni   = area_p + area_t - inter;
            float iou   = inter / (uni + EPSF);
            float cw = fmaxf(p.z, tx2) - fminf(p.x, tx1);
            float ch = fmaxf(p.w, ty2) - fminf(p.y, ty1);
            float area_c = cw * ch;
            ploc += 1.f - (iou - (area_c - uni) / (area_c + EPSF));
            pc++;
            v[i] = -1.f;                 // exclude from mining
        }
    }
    for (int off = 32; off; off >>= 1) {
        pc   += __shfl_xor(pc, off);
        pce  += __shfl_xor(pce, off);
        ploc += __shfl_xor(ploc, off);
    }
    if (lane == 0) {
        if (pc) atomicAdd(&nm_s, pc);
        atomicAdd(&fs[2], pce);
        atomicAdd(&fs[3], ploc);
    }

    // ---- count & sum of all mining candidates (v >= 0) ----
    int c = 0; float sa = 0.f;
    #pragma unroll
    for (int i = 0; i < VPT; ++i) { if (v[i] >= 0.f) { c++; sa += v[i]; } }
    for (int off = 32; off; off >>= 1) { c += __shfl_xor(c, off); sa += __shfl_xor(sa, off); }
    if (lane == 0) { atomicAdd(&cnt[32], c); atomicAdd(&fs[0], sa); }
    __syncthreads();

    int k = 3 * nm_s;
    int c0 = cnt[32]; float sall = fs[0];
    float negl = 0.f;
    if (k >= c0) {
        negl = sall;
    } else if (k > 0) {
        // bisect IEEE bits for the k-th largest candidate (values > 0)
        unsigned lo = 0u, hi = 0x7F800000u;
        int it = 0;
        while (hi - lo > 1u) {           // 31 uniform iterations
            unsigned mid = lo + (hi - lo) / 2u;
            float thr = __uint_as_float(mid);
            int cc = 0;
            #pragma unroll
            for (int i = 0; i < VPT; ++i) cc += (v[i] >= thr) ? 1 : 0;
            for (int off = 32; off; off >>= 1) cc += __shfl_xor(cc, off);
            if (lane == 0) atomicAdd(&cnt[it], cc);
            __syncthreads();
            if (cnt[it] >= k) lo = mid; else hi = mid;
            ++it;
        }
        float tth = __uint_as_float(lo); // exact k-th largest value
        int cg = 0; float sg = 0.f;
        #pragma unroll
        for (int i = 0; i < VPT; ++i) { if (v[i] > tth) { cg++; sg += v[i]; } }
        for (int off = 32; off; off >>= 1) { cg += __shfl_xor(cg, off); sg += __shfl_xor(sg, off); }
        if (lane == 0) { atomicAdd(&cnt[33], cg); atomicAdd(&fs[1], sg); }
        __syncthreads();
        negl = fs[1] + (float)(k - cnt[33]) * tth;   // ties contribute value tth
    }

    if (tid == 0) {
        atomicAdd(&accum[0], (double)(fs[2] + negl));
        atomicAdd(&accum[1], (double)fs[3]);
        atomicAdd(hits, (unsigned long long)nm_s);
    }
}

// ---------------- K3: finalize ----------------
__global__ void finalize_kernel(const double* __restrict__ accum,
                                const unsigned long long* __restrict__ hits,
                                float* __restrict__ out) {
    if (threadIdx.x == 0 && blockIdx.x == 0) {
        double conf_s = accum[0], loc_s = accum[1];
        unsigned long long h = *hits;
        double denom = (double)(h > 0 ? h : 1ull);
        if (h > 0) {
            out[0] = (float)((conf_s + loc_s) / denom);
            out[1] = (float)(conf_s / denom);
            out[2] = (float)(loc_s / denom);
        } else {
            out[0] = 0.f; out[1] = 0.f; out[2] = 0.f;
        }
    }
}

extern "C" void kernel_launch(void* const* d_in, const int* in_sizes, int n_in,
                              void* d_out, int out_size, void* d_ws, size_t ws_size,
                              hipStream_t stream) {
    const float* conf = (const float*)d_in[0];
    const float* loc  = (const float*)d_in[1];
    const float* tgt  = (const float*)d_in[2];
    float* out = (float*)d_out;

    char* ws = (char*)d_ws;
    float* sout = (float*)ws;
    double* accum = (double*)(ws + SBYTES);
    unsigned long long* hits = (unsigned long long*)(ws + SBYTES + 16);

    lse_kernel<<<dim3(GRID1), dim3(64), 0, stream>>>(conf, sout, accum, hits);
    mine_kernel<<<dim3(B_BATCH), dim3(K2_T), 0, stream>>>(
        conf, loc, tgt, sout, accum, hits);
    finalize_kernel<<<1, 64, 0, stream>>>(accum, hits, out);
}